// Round 7
// baseline (11959.520 us; speedup 1.0000x reference)
//
#include <hip/hip_runtime.h>

// ScaledODENetFE: forward-Euler scan, T=44100, B=32, F=1, S=16, H=64.
// Chain-latency bound. R18 = TWO BATCHES PER WAVE x R12's validated DS
// combine. Isolation experiment: R15/R17 both failed with permlane_swap
// self-operand pair-sum (asm AND builtin forms; 1.3e-2 / 8.5e-1) -> the
// construct "permlane*_swap with both operands = same value" is BANNED:
// backend may assign one physical reg to both tied operands, executing
// v_permlane16_swap vX,vX (in-place row shuffle; pair-sum -> 2*mirror).
// R14 passed by allocation luck. This round changes ONE thing vs R12
// (6571us, bit-exact): two independent recurrence chains interleaved in
// one issue stream. The DS round-trip (~130cy) stays on each chain but is
// now hidden by the OTHER chain's ~130cy of issue - which is the entire
// point of dual-batch. All FP trees bit-identical to R12 -> absmax must
// be exactly 4.768e-07.
// R13 lesson: never add issue ON the chain to remove latency.
// Kept from R12: 3-independent-DS cross-row combine (^16 swizzle, ^32/^48
// bpermute), constant-64 main loop + peeled last step + 3-step tail,
// unroll 9, pk-packed 16-readlane dot, r-form with -2-scaled W2, K-fold
// carry, zbase precompute off-chain.
// LDS P-broadcast BANNED (R7). R10's V-reconstruction BANNED (carry noise).

#define SRATE 44100.0f
#define T_TOTAL 44100
#define BATCH 32
#define HID 64
#define ST 16
#define KSCALE 2.8853900817779268f   // 2*log2(e)

typedef float v2f __attribute__((ext_vector_type(2)));

template <int CTRL>
__device__ __forceinline__ float dppmov(float x) {
    return __builtin_bit_cast(float,
        __builtin_amdgcn_update_dpp(0, __builtin_bit_cast(int, x),
                                    CTRL, 0xF, 0xF, false));
}

__device__ __forceinline__ float bcast(float v, int lane) {
    return __builtin_bit_cast(float,
        __builtin_amdgcn_readlane(__builtin_bit_cast(int, v), lane));
}

__device__ __forceinline__ int parity(int v) { return __builtin_popcount(v) & 1; }

__global__ __launch_bounds__(64, 1)
void ScaledODENetFE_kernel(const float* __restrict__ x,
                           const float* __restrict__ W1,
                           const float* __restrict__ b1,
                           const float* __restrict__ W2,
                           const float* __restrict__ b2v,
                           float* __restrict__ out) {
    const int b0 = 2 * blockIdx.x;      // first batch element
    const int b1i = b0 + 1;             // second batch element
    const int lane = threadIdx.x;       // hidden unit k
    const int TM1 = T_TOTAL - 1;        // 44099 scan steps = 689*64 + 3
    const int NFULL = 689;

    // ---- one-time precompute (lane k) — batch-invariant ----
    const float w1xK = W1[lane] * KSCALE;       // K-scaled x weight
    float w1yd[ST];                             // K * W1[1+s][lane] / sr
    #pragma unroll
    for (int s = 0; s < ST; ++s)
        w1yd[s] = (W1[(1 + s) * HID + lane] / SRATE) * KSCALE;

    // C2 = sum_s (b2[s] + pconst_s) * w1yd[s];  pconst_s = sum_k W2[k,s].
    float C2 = 0.f;
    #pragma unroll
    for (int s = 0; s < ST; ++s) C2 = fmaf(b2v[s], w1yd[s], C2);
    float pconst0 = 0.f;
    for (int s = 0; s < ST; ++s) {
        float pc = 0.f;
        for (int k = 0; k < HID; ++k) pc += W2[k * ST + s];
        C2 = fmaf(pc, w1yd[s], C2);
        if (s == 0) pconst0 = pc;
    }
    // pk-dot weight pairs (per-lane VGPR pairs).
    v2f wy2[8];
    #pragma unroll
    for (int m = 0; m < 8; ++m) wy2[m] = (v2f){w1yd[2 * m], w1yd[2 * m + 1]};
    const v2f C2v = (v2f){C2, 0.f};             // loop-invariant seed

    // Dual-basis lane phis for the permuted W2 layout (XOR gens 1,2,7,8),
    // weights pre-scaled by -2 (r-form: p = pconst - 2 * W2^T r).
    const int p1 = parity(lane & 5), p2 = parity(lane & 6);
    const int p3 = (lane >> 2) & 1, p4 = (lane >> 3) & 1;
    float wA[8], wB[8];
    #pragma unroll
    for (int j = 0; j < 8; ++j) {
        const int i = 2 * j;
        const int c1 = (i & 1) ^ p1;
        const int c2 = ((i >> 1) & 1) ^ p2;
        const int c3 = ((i >> 2) & 1) ^ p3;
        const int c4 = ((i >> 3) & 1) ^ p4;
        const int s = (c1 ? 1 : 0) ^ (c2 ? 2 : 0) ^ (c3 ? 7 : 0) ^ (c4 ? 8 : 0);
        wA[j] = -2.f * W2[lane * ST + s];
        wB[j] = -2.f * W2[(lane ^ 1) * ST + s];
    }
    v2f wA2[4], wB2[4];
    #pragma unroll
    for (int m = 0; m < 4; ++m) {
        wA2[m] = (v2f){wA[2 * m], wA[2 * m + 1]};
        wB2[m] = (v2f){wB[2 * m], wB[2 * m + 1]};
    }

    const int bp32 = ((lane ^ 32) & 63) << 2;   // ds_bpermute byte addrs
    const int bp48 = ((lane ^ 48) & 63) << 2;
    const float b20 = b2v[0];

    // ---- per-batch state ----
    float VA = b1[lane] * KSCALE, VB = VA;      // K-scaled carries (y starts 0)
    float y0A = 0.f, y0B = 0.f;

    if (lane == 0) { out[b0] = 0.f; out[b1i] = 0.f; }   // row t=0 is zeros

    // Lane l holds x[(t0+l)*B + b]; prefetch one chunk ahead.
    float xvA = x[lane * BATCH + b0];
    float xvB = x[lane * BATCH + b1i];
    float zA = fmaf(bcast(xvA, 0), w1xK, VA);   // z_0 (K-scaled)
    float zB = fmaf(bcast(xvB, 0), w1xK, VB);

    // One recurrence step for one batch's state (z, V); returns pb0.
    // Byte-identical arithmetic to R12's validated STEP.
    auto STEP = [&](float& z, float& V, float xtn, float& pb0) {
        // tanh in r-form: t=exp2(z); r=rcp(t+1). (h = 1-2r implicit;
        // saturation via inf/0 semantics, no clamp — R8-validated.)
        float t = __builtin_amdgcn_exp2f(z);
        float r = __builtin_amdgcn_rcpf(t + 1.f);

        // Off-chain prep for next step's z (uses pre-update V; +R applied once).
        float zbase = fmaf(xtn, w1xK, V);

        // Stage 1 (xor1, fused, packed) on r with -2-scaled weights.
        float rx = dppmov<0xB1>(r);             // quad_perm [1,0,3,2]
        v2f r2v = (v2f){r, r};
        v2f rx2 = (v2f){rx, rx};
        v2f u1p[4];
        #pragma unroll
        for (int m = 0; m < 4; ++m)
            u1p[m] = __builtin_elementwise_fma(rx2, wB2[m], r2v * wA2[m]);

        // Stage 2 (xor2 = quad_perm [2,3,0,1]).
        float u2[4];
        #pragma unroll
        for (int m = 0; m < 4; ++m)
            u2[m] = u1p[m].x + dppmov<0x4E>(u1p[m].y);

        // Stage 3 (xor7 = row_half_mirror).
        float u3a = u2[0] + dppmov<0x141>(u2[1]);
        float u3b = u2[2] + dppmov<0x141>(u2[3]);

        // Stage 4 (xor8 = row_ror:8).
        float Pb = u3a + dppmov<0x128>(u3b);
        // Lane l now holds its ROW's partial sum for s = l&15.

        // Cross-row combine: 3 INDEPENDENT DS ops, one latency (R6).
        // Hidden by the OTHER batch's issue stream in the dual-chain pair.
        int   Pi  = __builtin_bit_cast(int, Pb);
        float a16 = __builtin_bit_cast(float,
                    __builtin_amdgcn_ds_swizzle(Pi, 0x401F));       // ^16
        float a32 = __builtin_bit_cast(float,
                    __builtin_amdgcn_ds_bpermute(bp32, Pi));        // ^32
        float a48 = __builtin_bit_cast(float,
                    __builtin_amdgcn_ds_bpermute(bp48, Pi));        // ^48
        float Pc = (Pb + a16) + (a32 + a48);
        // Lane holds Pc_{lane&15}; p_s = pconst_s + Pc_s.

        // R = C2 + sum_s Pc_s*w1yd[s]: pk-packed, 2 chains of 4 pk_fma.
        // Broadcast pairs are wave-uniform -> SGPR-pair scalar operands.
        v2f p01 = (v2f){bcast(Pc, 0),  bcast(Pc, 1)};
        v2f p23 = (v2f){bcast(Pc, 2),  bcast(Pc, 3)};
        v2f p45 = (v2f){bcast(Pc, 4),  bcast(Pc, 5)};
        v2f p67 = (v2f){bcast(Pc, 6),  bcast(Pc, 7)};
        v2f p89 = (v2f){bcast(Pc, 8),  bcast(Pc, 9)};
        v2f pAB = (v2f){bcast(Pc, 10), bcast(Pc, 11)};
        v2f pCD = (v2f){bcast(Pc, 12), bcast(Pc, 13)};
        v2f pEF = (v2f){bcast(Pc, 14), bcast(Pc, 15)};
        v2f acc_a = __builtin_elementwise_fma(p01, wy2[0], C2v);
        acc_a = __builtin_elementwise_fma(p23, wy2[1], acc_a);
        acc_a = __builtin_elementwise_fma(p45, wy2[2], acc_a);
        acc_a = __builtin_elementwise_fma(p67, wy2[3], acc_a);
        v2f acc_b = p89 * wy2[4];
        acc_b = __builtin_elementwise_fma(pAB, wy2[5], acc_b);
        acc_b = __builtin_elementwise_fma(pCD, wy2[6], acc_b);
        acc_b = __builtin_elementwise_fma(pEF, wy2[7], acc_b);
        v2f accs = acc_a + acc_b;
        float R = accs.x + accs.y;

        pb0 = p01.x;         // combined Pb0 for the y0 path (CSE'd readlane)
        z = zbase + R;       // critical-path tail: single add
        V = V + R;           // off-chain, feeds next step's zbase
    };

    // ---- 689 full 64-step blocks ----
    for (int blk = 0; blk < NFULL; ++blk) {
        const int t0 = blk * 64;
        // Next chunks; first touched at the peeled step (63 steps later),
        // so their vmcnt waits are fully hidden.
        const int nidx = min(t0 + 64 + lane, TM1 - 1) * BATCH;
        float xvnA = x[nidx + b0];
        float xvnB = x[nidx + b1i];
        float outyA = 0.f, outyB = 0.f;
        float pb0A, pb0B;

        #pragma unroll 9
        for (int kk = 0; kk < 63; ++kk) {
            // Two independent chains interleave in the issue stream.
            STEP(zA, VA, bcast(xvA, kk + 1), pb0A);
            STEP(zB, VB, bcast(xvB, kk + 1), pb0B);
            y0A += pconst0 + pb0A;
            outyA = (kk == lane) ? y0A : outyA;
            y0B += pconst0 + pb0B;
            outyB = (kk == lane) ? y0B : outyB;
        }
        // Peeled kk=63: next-x comes from lane 0 of the prefetched chunks.
        STEP(zA, VA, bcast(xvnA, 0), pb0A);
        y0A += pconst0 + pb0A;
        outyA = (63 == lane) ? y0A : outyA;
        STEP(zB, VB, bcast(xvnB, 0), pb0B);
        y0B += pconst0 + pb0B;
        outyB = (63 == lane) ? y0B : outyB;

        // Store: add back n*b2[0], one IEEE div per batch, coalesced.
        const int n = t0 + 1 + lane;
        out[n * BATCH + b0]  = fmaf((float)n, b20, outyA) / SRATE;
        out[n * BATCH + b1i] = fmaf((float)n, b20, outyB) / SRATE;
        xvA = xvnA;
        xvB = xvnB;
    }

    // ---- tail: 3 steps (n = 44097..44099) ----
    {
        const int t0 = NFULL * 64;              // 44096
        float outyA = 0.f, outyB = 0.f;
        float pb0A, pb0B;
        #pragma unroll
        for (int kk = 0; kk < 3; ++kk) {
            STEP(zA, VA, bcast(xvA, kk + 1), pb0A);
            STEP(zB, VB, bcast(xvB, kk + 1), pb0B);
            y0A += pconst0 + pb0A;
            outyA = (kk == lane) ? y0A : outyA;
            y0B += pconst0 + pb0B;
            outyB = (kk == lane) ? y0B : outyB;
        }
        if (lane < 3) {
            const int n = t0 + 1 + lane;
            out[n * BATCH + b0]  = fmaf((float)n, b20, outyA) / SRATE;
            out[n * BATCH + b1i] = fmaf((float)n, b20, outyB) / SRATE;
        }
    }
}

extern "C" void kernel_launch(void* const* d_in, const int* in_sizes, int n_in,
                              void* d_out, int out_size, void* d_ws, size_t ws_size,
                              hipStream_t stream) {
    const float* x  = (const float*)d_in[0];
    const float* W1 = (const float*)d_in[1];
    const float* b1 = (const float*)d_in[2];
    const float* W2 = (const float*)d_in[3];
    const float* b2 = (const float*)d_in[4];
    float* out = (float*)d_out;

    ScaledODENetFE_kernel<<<BATCH / 2, 64, 0, stream>>>(x, W1, b1, W2, b2, out);
}

// Round 8
// 11181.204 us; speedup vs baseline: 1.0696x; 1.0696x over previous
//
#include <hip/hip_runtime.h>

// ScaledODENetFE: forward-Euler scan, T=44100, B=32, F=1, S=16, H=64.
// Chain-latency bound. R19 = R18 (dual-batch, validated bit-exact) with
// the two chains MANUALLY INTERLEAVED in source order (fused STEP2).
// R18 post-mortem: compiler executed STEP A then STEP B serially (648
// cy/pair = 2x324; VALUBusy halved) — the scheduler does NOT discover
// cross-chain ILP from sequential source at 1200-instr block scale.
// STEP2 phase structure (each chain's stall covered by the other's issue):
//   P1: fronts A,B (exp2/rcp/zbase, trans latencies overlap)
//   P2: butterfly A -> issue A's 3 DS ops
//   P3: butterfly B (~50cy issue, covers A's DS round trip) -> issue B's DS
//   P4: wait A (lgkmcnt(3), B's in flight) -> combine+dot+update A
//       (~55cy, covers B's DS round trip)
//   P5: wait B (lgkmcnt(0)) -> combine+dot+update B
// Per-chain FP trees byte-identical to R12/R18 -> absmax must stay exactly
// 4.768372e-07. Unroll 9->3 (pair body ~2x instr; keeps block ~R12-sized,
// divides 63).
// permlane*_swap with self-operands BANNED (R15 asm + R17 builtin both
// miscompiled; backend may fold both tied operands onto one phys reg ->
// in-place shuffle). R13 lesson: never add issue ON the chain.
// Kept from R12: 3-independent-DS combine, constant-64 main loop + peeled
// last step + 3-step tail, pk-packed 16-readlane dot, r-form with
// -2-scaled W2, K-fold carry, zbase off-chain.
// LDS P-broadcast BANNED (R7). R10's V-reconstruction BANNED (carry noise).

#define SRATE 44100.0f
#define T_TOTAL 44100
#define BATCH 32
#define HID 64
#define ST 16
#define KSCALE 2.8853900817779268f   // 2*log2(e)

typedef float v2f __attribute__((ext_vector_type(2)));

template <int CTRL>
__device__ __forceinline__ float dppmov(float x) {
    return __builtin_bit_cast(float,
        __builtin_amdgcn_update_dpp(0, __builtin_bit_cast(int, x),
                                    CTRL, 0xF, 0xF, false));
}

__device__ __forceinline__ float bcast(float v, int lane) {
    return __builtin_bit_cast(float,
        __builtin_amdgcn_readlane(__builtin_bit_cast(int, v), lane));
}

__device__ __forceinline__ int parity(int v) { return __builtin_popcount(v) & 1; }

__global__ __launch_bounds__(64, 1)
void ScaledODENetFE_kernel(const float* __restrict__ x,
                           const float* __restrict__ W1,
                           const float* __restrict__ b1,
                           const float* __restrict__ W2,
                           const float* __restrict__ b2v,
                           float* __restrict__ out) {
    const int b0 = 2 * blockIdx.x;      // first batch element
    const int b1i = b0 + 1;             // second batch element
    const int lane = threadIdx.x;       // hidden unit k
    const int TM1 = T_TOTAL - 1;        // 44099 scan steps = 689*64 + 3
    const int NFULL = 689;

    // ---- one-time precompute (lane k) — batch-invariant ----
    const float w1xK = W1[lane] * KSCALE;       // K-scaled x weight
    float w1yd[ST];                             // K * W1[1+s][lane] / sr
    #pragma unroll
    for (int s = 0; s < ST; ++s)
        w1yd[s] = (W1[(1 + s) * HID + lane] / SRATE) * KSCALE;

    // C2 = sum_s (b2[s] + pconst_s) * w1yd[s];  pconst_s = sum_k W2[k,s].
    float C2 = 0.f;
    #pragma unroll
    for (int s = 0; s < ST; ++s) C2 = fmaf(b2v[s], w1yd[s], C2);
    float pconst0 = 0.f;
    for (int s = 0; s < ST; ++s) {
        float pc = 0.f;
        for (int k = 0; k < HID; ++k) pc += W2[k * ST + s];
        C2 = fmaf(pc, w1yd[s], C2);
        if (s == 0) pconst0 = pc;
    }
    // pk-dot weight pairs (per-lane VGPR pairs).
    v2f wy2[8];
    #pragma unroll
    for (int m = 0; m < 8; ++m) wy2[m] = (v2f){w1yd[2 * m], w1yd[2 * m + 1]};
    const v2f C2v = (v2f){C2, 0.f};             // loop-invariant seed

    // Dual-basis lane phis for the permuted W2 layout (XOR gens 1,2,7,8),
    // weights pre-scaled by -2 (r-form: p = pconst - 2 * W2^T r).
    const int p1 = parity(lane & 5), p2 = parity(lane & 6);
    const int p3 = (lane >> 2) & 1, p4 = (lane >> 3) & 1;
    float wA[8], wB[8];
    #pragma unroll
    for (int j = 0; j < 8; ++j) {
        const int i = 2 * j;
        const int c1 = (i & 1) ^ p1;
        const int c2 = ((i >> 1) & 1) ^ p2;
        const int c3 = ((i >> 2) & 1) ^ p3;
        const int c4 = ((i >> 3) & 1) ^ p4;
        const int s = (c1 ? 1 : 0) ^ (c2 ? 2 : 0) ^ (c3 ? 7 : 0) ^ (c4 ? 8 : 0);
        wA[j] = -2.f * W2[lane * ST + s];
        wB[j] = -2.f * W2[(lane ^ 1) * ST + s];
    }
    v2f wA2[4], wB2[4];
    #pragma unroll
    for (int m = 0; m < 4; ++m) {
        wA2[m] = (v2f){wA[2 * m], wA[2 * m + 1]};
        wB2[m] = (v2f){wB[2 * m], wB[2 * m + 1]};
    }

    const int bp32 = ((lane ^ 32) & 63) << 2;   // ds_bpermute byte addrs
    const int bp48 = ((lane ^ 48) & 63) << 2;
    const float b20 = b2v[0];

    // ---- per-batch state ----
    float VA = b1[lane] * KSCALE, VB = VA;      // K-scaled carries (y starts 0)
    float y0A = 0.f, y0B = 0.f;

    if (lane == 0) { out[b0] = 0.f; out[b1i] = 0.f; }   // row t=0 is zeros

    // Lane l holds x[(t0+l)*B + b]; prefetch one chunk ahead.
    float xvA = x[lane * BATCH + b0];
    float xvB = x[lane * BATCH + b1i];
    float zA = fmaf(bcast(xvA, 0), w1xK, VA);   // z_0 (K-scaled)
    float zB = fmaf(bcast(xvB, 0), w1xK, VB);

    // Butterfly (stages 1-4) on r: returns Pb (row partial for s = lane&15).
    auto BFLY = [&](float r) -> float {
        float rx = dppmov<0xB1>(r);             // quad_perm [1,0,3,2]
        v2f r2v = (v2f){r, r};
        v2f rx2 = (v2f){rx, rx};
        v2f u1p[4];
        #pragma unroll
        for (int m = 0; m < 4; ++m)
            u1p[m] = __builtin_elementwise_fma(rx2, wB2[m], r2v * wA2[m]);
        float u2[4];
        #pragma unroll
        for (int m = 0; m < 4; ++m)
            u2[m] = u1p[m].x + dppmov<0x4E>(u1p[m].y);
        float u3a = u2[0] + dppmov<0x141>(u2[1]);
        float u3b = u2[2] + dppmov<0x141>(u2[3]);
        return u3a + dppmov<0x128>(u3b);        // row_ror:8
    };

    // Combine + pk-dot + state update for one chain (consumes DS results).
    auto FINISH = [&](float Pb, float a16, float a32, float a48,
                      float zbase, float& z, float& V, float& pb0) {
        float Pc = (Pb + a16) + (a32 + a48);
        v2f p01 = (v2f){bcast(Pc, 0),  bcast(Pc, 1)};
        v2f p23 = (v2f){bcast(Pc, 2),  bcast(Pc, 3)};
        v2f p45 = (v2f){bcast(Pc, 4),  bcast(Pc, 5)};
        v2f p67 = (v2f){bcast(Pc, 6),  bcast(Pc, 7)};
        v2f p89 = (v2f){bcast(Pc, 8),  bcast(Pc, 9)};
        v2f pAB = (v2f){bcast(Pc, 10), bcast(Pc, 11)};
        v2f pCD = (v2f){bcast(Pc, 12), bcast(Pc, 13)};
        v2f pEF = (v2f){bcast(Pc, 14), bcast(Pc, 15)};
        v2f acc_a = __builtin_elementwise_fma(p01, wy2[0], C2v);
        acc_a = __builtin_elementwise_fma(p23, wy2[1], acc_a);
        acc_a = __builtin_elementwise_fma(p45, wy2[2], acc_a);
        acc_a = __builtin_elementwise_fma(p67, wy2[3], acc_a);
        v2f acc_b = p89 * wy2[4];
        acc_b = __builtin_elementwise_fma(pAB, wy2[5], acc_b);
        acc_b = __builtin_elementwise_fma(pCD, wy2[6], acc_b);
        acc_b = __builtin_elementwise_fma(pEF, wy2[7], acc_b);
        v2f accs = acc_a + acc_b;
        float R = accs.x + accs.y;
        pb0 = p01.x;
        z = zbase + R;       // critical-path tail: single add
        V = V + R;           // off-chain, feeds next step's zbase
    };

    // Fused dual-chain step: phases ordered so each chain's DS round trip
    // is covered by the other chain's issue. FP trees per chain identical
    // to R12 -> bit-identical results.
    auto STEP2 = [&](float xtnA, float& pb0A, float xtnB, float& pb0B) {
        // P1: fronts, interleaved (two trans latencies overlap).
        float tA = __builtin_amdgcn_exp2f(zA);
        float tB = __builtin_amdgcn_exp2f(zB);
        float rA = __builtin_amdgcn_rcpf(tA + 1.f);
        float rB = __builtin_amdgcn_rcpf(tB + 1.f);
        float zbaseA = fmaf(xtnA, w1xK, VA);
        float zbaseB = fmaf(xtnB, w1xK, VB);

        // P2: butterfly A, issue A's DS trio.
        float PbA = BFLY(rA);
        int PiA = __builtin_bit_cast(int, PbA);
        float a16A = __builtin_bit_cast(float,
                     __builtin_amdgcn_ds_swizzle(PiA, 0x401F));      // ^16
        float a32A = __builtin_bit_cast(float,
                     __builtin_amdgcn_ds_bpermute(bp32, PiA));       // ^32
        float a48A = __builtin_bit_cast(float,
                     __builtin_amdgcn_ds_bpermute(bp48, PiA));       // ^48

        // P3: butterfly B (covers A's DS round trip), issue B's DS trio.
        float PbB = BFLY(rB);
        int PiB = __builtin_bit_cast(int, PbB);
        float a16B = __builtin_bit_cast(float,
                     __builtin_amdgcn_ds_swizzle(PiB, 0x401F));
        float a32B = __builtin_bit_cast(float,
                     __builtin_amdgcn_ds_bpermute(bp32, PiB));
        float a48B = __builtin_bit_cast(float,
                     __builtin_amdgcn_ds_bpermute(bp48, PiB));

        // P4: finish A (waits lgkmcnt(3): B's trio stays in flight);
        //     A's dot issue covers B's DS round trip.
        FINISH(PbA, a16A, a32A, a48A, zbaseA, zA, VA, pb0A);

        // P5: finish B (waits lgkmcnt(0)).
        FINISH(PbB, a16B, a32B, a48B, zbaseB, zB, VB, pb0B);
    };

    // ---- 689 full 64-step blocks ----
    for (int blk = 0; blk < NFULL; ++blk) {
        const int t0 = blk * 64;
        // Next chunks; first touched at the peeled step (63 steps later),
        // so their vmcnt waits are fully hidden.
        const int nidx = min(t0 + 64 + lane, TM1 - 1) * BATCH;
        float xvnA = x[nidx + b0];
        float xvnB = x[nidx + b1i];
        float outyA = 0.f, outyB = 0.f;
        float pb0A, pb0B;

        #pragma unroll 3
        for (int kk = 0; kk < 63; ++kk) {
            STEP2(bcast(xvA, kk + 1), pb0A, bcast(xvB, kk + 1), pb0B);
            y0A += pconst0 + pb0A;
            outyA = (kk == lane) ? y0A : outyA;
            y0B += pconst0 + pb0B;
            outyB = (kk == lane) ? y0B : outyB;
        }
        // Peeled kk=63: next-x comes from lane 0 of the prefetched chunks.
        STEP2(bcast(xvnA, 0), pb0A, bcast(xvnB, 0), pb0B);
        y0A += pconst0 + pb0A;
        outyA = (63 == lane) ? y0A : outyA;
        y0B += pconst0 + pb0B;
        outyB = (63 == lane) ? y0B : outyB;

        // Store: add back n*b2[0], one IEEE div per batch, coalesced.
        const int n = t0 + 1 + lane;
        out[n * BATCH + b0]  = fmaf((float)n, b20, outyA) / SRATE;
        out[n * BATCH + b1i] = fmaf((float)n, b20, outyB) / SRATE;
        xvA = xvnA;
        xvB = xvnB;
    }

    // ---- tail: 3 steps (n = 44097..44099) ----
    {
        const int t0 = NFULL * 64;              // 44096
        float outyA = 0.f, outyB = 0.f;
        float pb0A, pb0B;
        #pragma unroll
        for (int kk = 0; kk < 3; ++kk) {
            STEP2(bcast(xvA, kk + 1), pb0A, bcast(xvB, kk + 1), pb0B);
            y0A += pconst0 + pb0A;
            outyA = (kk == lane) ? y0A : outyA;
            y0B += pconst0 + pb0B;
            outyB = (kk == lane) ? y0B : outyB;
        }
        if (lane < 3) {
            const int n = t0 + 1 + lane;
            out[n * BATCH + b0]  = fmaf((float)n, b20, outyA) / SRATE;
            out[n * BATCH + b1i] = fmaf((float)n, b20, outyB) / SRATE;
        }
    }
}

extern "C" void kernel_launch(void* const* d_in, const int* in_sizes, int n_in,
                              void* d_out, int out_size, void* d_ws, size_t ws_size,
                              hipStream_t stream) {
    const float* x  = (const float*)d_in[0];
    const float* W1 = (const float*)d_in[1];
    const float* b1 = (const float*)d_in[2];
    const float* W2 = (const float*)d_in[3];
    const float* b2 = (const float*)d_in[4];
    float* out = (float*)d_out;

    ScaledODENetFE_kernel<<<BATCH / 2, 64, 0, stream>>>(x, W1, b1, W2, b2, out);
}

// Round 9
// 5773.404 us; speedup vs baseline: 2.0715x; 1.9367x over previous
//
#include <hip/hip_runtime.h>

// ScaledODENetFE: forward-Euler scan, T=44100, B=32, F=1, S=16, H=64.
// One wave per batch; lane k owns hidden unit k. Chain-latency bound.
// R14 = R12 (6571us kernel) with ONE delta: the cross-row DS combine
// (3x ds_swizzle/bpermute, ~120-200cy round trip ON the chain) is replaced
// by permlane16/32 swaps (VALU, ~8cy each) using the pair-sum idiom:
//   with a=b=Pb, after v_permlane16_swap_b32 a,b the two regs jointly hold
//   lanes {l, l^16}, so a+b = Pb_l + Pb_{l^16} under any swap orientation;
//   repeat with 32-swap -> Pc = (Pb+Pb16) + (Pb32+Pb48), the SAME rounding
//   tree as R12's DS combine (absmax must stay bit-identical).
// Re-litigating the R4/R5 permlane ban deliberately: catalog evidence
// (m255: permlane32_swap 1.20x ds_bpermute even in THROUGHPUT; T12 uses it
// in production) + this is a LATENCY chain (~15x latency gap). Suspected
// original ban cause: swap used as a pure function (it writes BOTH
// operands) -> wrong results. The "+v","+v" inline-asm form encodes the
// dual-write exactly; pair-sum makes orientation irrelevant.
// R13 readlane-all REVERTED (+60% regression): 48 extra readlanes + v2f
// packing movs serialized ON the chain. Post-DS broadcast stays at 16
// readlanes; never add issue on the chain to remove latency.
// Kept from R12: constant-64 main loop + peeled last step + 3-step tail,
// unroll 9, pk-packed 16-readlane dot, r-form with -2-scaled W2, K-fold
// carry, zbase precompute off-chain.
// LDS P-broadcast BANNED (R7). R10's V-reconstruction BANNED (carry noise).
//
// [R20 NOTE] This is a BYTE-EXACT resubmission of the R14 source that
// passed at 5704-5755us with absmax 4.768372e-07. R15-R19 established:
// (1) dual-batch-per-wave is structurally unable to beat single-batch
//     (wall = 44099 x chain-latency; batches already CU-parallel);
// (2) permlane_swap self-operand forms are allocation-fragile in ANY
//     other register-pressure context (R15 asm FAIL, R17 builtin FAIL) --
//     do NOT perturb this source; hipcc is deterministic, so the exact
//     source reproduces the exact passing binary.

#define SRATE 44100.0f
#define T_TOTAL 44100
#define BATCH 32
#define HID 64
#define ST 16
#define KSCALE 2.8853900817779268f   // 2*log2(e)

typedef float v2f __attribute__((ext_vector_type(2)));

template <int CTRL>
__device__ __forceinline__ float dppmov(float x) {
    return __builtin_bit_cast(float,
        __builtin_amdgcn_update_dpp(0, __builtin_bit_cast(int, x),
                                    CTRL, 0xF, 0xF, false));
}

__device__ __forceinline__ float bcast(float v, int lane) {
    return __builtin_bit_cast(float,
        __builtin_amdgcn_readlane(__builtin_bit_cast(int, v), lane));
}

__device__ __forceinline__ int parity(int v) { return __builtin_popcount(v) & 1; }

__global__ __launch_bounds__(64, 1)
void ScaledODENetFE_kernel(const float* __restrict__ x,
                           const float* __restrict__ W1,
                           const float* __restrict__ b1,
                           const float* __restrict__ W2,
                           const float* __restrict__ b2v,
                           float* __restrict__ out) {
    const int b = blockIdx.x;      // batch element
    const int lane = threadIdx.x;  // hidden unit k
    const int TM1 = T_TOTAL - 1;   // 44099 scan steps = 689*64 + 3
    const int NFULL = 689;

    // ---- one-time precompute (lane k) ----
    const float w1xK = W1[lane] * KSCALE;       // K-scaled x weight
    float w1yd[ST];                             // K * W1[1+s][lane] / sr
    #pragma unroll
    for (int s = 0; s < ST; ++s)
        w1yd[s] = (W1[(1 + s) * HID + lane] / SRATE) * KSCALE;

    // C2 = sum_s (b2[s] + pconst_s) * w1yd[s];  pconst_s = sum_k W2[k,s].
    float C2 = 0.f;
    #pragma unroll
    for (int s = 0; s < ST; ++s) C2 = fmaf(b2v[s], w1yd[s], C2);
    float pconst0 = 0.f;
    for (int s = 0; s < ST; ++s) {
        float pc = 0.f;
        for (int k = 0; k < HID; ++k) pc += W2[k * ST + s];
        C2 = fmaf(pc, w1yd[s], C2);
        if (s == 0) pconst0 = pc;
    }
    // pk-dot weight pairs (per-lane VGPR pairs).
    v2f wy2[8];
    #pragma unroll
    for (int m = 0; m < 8; ++m) wy2[m] = (v2f){w1yd[2 * m], w1yd[2 * m + 1]};
    const v2f C2v = (v2f){C2, 0.f};             // loop-invariant seed

    // Dual-basis lane phis for the permuted W2 layout (XOR gens 1,2,7,8),
    // weights pre-scaled by -2 (r-form: p = pconst - 2 * W2^T r).
    const int p1 = parity(lane & 5), p2 = parity(lane & 6);
    const int p3 = (lane >> 2) & 1, p4 = (lane >> 3) & 1;
    float wA[8], wB[8];
    #pragma unroll
    for (int j = 0; j < 8; ++j) {
        const int i = 2 * j;
        const int c1 = (i & 1) ^ p1;
        const int c2 = ((i >> 1) & 1) ^ p2;
        const int c3 = ((i >> 2) & 1) ^ p3;
        const int c4 = ((i >> 3) & 1) ^ p4;
        const int s = (c1 ? 1 : 0) ^ (c2 ? 2 : 0) ^ (c3 ? 7 : 0) ^ (c4 ? 8 : 0);
        wA[j] = -2.f * W2[lane * ST + s];
        wB[j] = -2.f * W2[(lane ^ 1) * ST + s];
    }
    v2f wA2[4], wB2[4];
    #pragma unroll
    for (int m = 0; m < 4; ++m) {
        wA2[m] = (v2f){wA[2 * m], wA[2 * m + 1]};
        wB2[m] = (v2f){wB[2 * m], wB[2 * m + 1]};
    }

    const float b20 = b2v[0];

    float V  = b1[lane] * KSCALE;               // K-scaled carry (y starts 0)
    float y0 = 0.f;

    if (lane == 0) out[b] = 0.f;                // row t=0 is zeros

    // Lane l holds x[(t0+l)*B + b]; prefetch one chunk ahead.
    float xv = x[lane * BATCH + b];
    float z = fmaf(bcast(xv, 0), w1xK, V);      // z_0 (K-scaled)

    // One recurrence step. Consumes z; produces next z, updates V; returns
    // this step's combined Pb0 (for the y0 path) through pb0.
    auto STEP = [&](float xtn, float& pb0) {
        // tanh in r-form: t=exp2(z); r=rcp(t+1). (h = 1-2r implicit;
        // saturation via inf/0 semantics, no clamp — R8-validated.)
        float t = __builtin_amdgcn_exp2f(z);
        float r = __builtin_amdgcn_rcpf(t + 1.f);

        // Off-chain prep for next step's z (uses pre-update V; +R applied once).
        float zbase = fmaf(xtn, w1xK, V);

        // Stage 1 (xor1, fused, packed) on r with -2-scaled weights.
        float rx = dppmov<0xB1>(r);             // quad_perm [1,0,3,2]
        v2f r2v = (v2f){r, r};
        v2f rx2 = (v2f){rx, rx};
        v2f u1p[4];
        #pragma unroll
        for (int m = 0; m < 4; ++m)
            u1p[m] = __builtin_elementwise_fma(rx2, wB2[m], r2v * wA2[m]);

        // Stage 2 (xor2 = quad_perm [2,3,0,1]).
        float u2[4];
        #pragma unroll
        for (int m = 0; m < 4; ++m)
            u2[m] = u1p[m].x + dppmov<0x4E>(u1p[m].y);

        // Stage 3 (xor7 = row_half_mirror).
        float u3a = u2[0] + dppmov<0x141>(u2[1]);
        float u3b = u2[2] + dppmov<0x141>(u2[3]);

        // Stage 4 (xor8 = row_ror:8).
        float Pb = u3a + dppmov<0x128>(u3b);
        // Lane l now holds its ROW's partial sum for s = l&15.

        // Cross-row combine via permlane swaps (VALU latency, no DS).
        // Pair-sum idiom: a=b=Pb; after the swap the two regs jointly hold
        // lanes {l, l^16}, so a+b = Pb_l + Pb_{l^16} regardless of swap
        // orientation. Then 32-swap on the sum. Rounding tree identical to
        // R12's (Pb + a16) + (a32 + a48).
        float sa = Pb, sb = Pb;
        asm("v_permlane16_swap_b32 %0, %1" : "+v"(sa), "+v"(sb));
        float y16 = sa + sb;                    // Pb_l + Pb_{l^16}
        float sc = y16, sd = y16;
        asm("v_permlane32_swap_b32 %0, %1" : "+v"(sc), "+v"(sd));
        float Pc = sc + sd;                     // full 4-row sum
        // Lane holds Pc_{lane&15}; p_s = pconst_s + Pc_s.

        // R = C2 + sum_s Pc_s*w1yd[s]: pk-packed, 2 chains of 4 pk_fma.
        // Broadcast pairs are wave-uniform -> SGPR-pair scalar operands.
        v2f p01 = (v2f){bcast(Pc, 0),  bcast(Pc, 1)};
        v2f p23 = (v2f){bcast(Pc, 2),  bcast(Pc, 3)};
        v2f p45 = (v2f){bcast(Pc, 4),  bcast(Pc, 5)};
        v2f p67 = (v2f){bcast(Pc, 6),  bcast(Pc, 7)};
        v2f p89 = (v2f){bcast(Pc, 8),  bcast(Pc, 9)};
        v2f pAB = (v2f){bcast(Pc, 10), bcast(Pc, 11)};
        v2f pCD = (v2f){bcast(Pc, 12), bcast(Pc, 13)};
        v2f pEF = (v2f){bcast(Pc, 14), bcast(Pc, 15)};
        v2f acc_a = __builtin_elementwise_fma(p01, wy2[0], C2v);
        acc_a = __builtin_elementwise_fma(p23, wy2[1], acc_a);
        acc_a = __builtin_elementwise_fma(p45, wy2[2], acc_a);
        acc_a = __builtin_elementwise_fma(p67, wy2[3], acc_a);
        v2f acc_b = p89 * wy2[4];
        acc_b = __builtin_elementwise_fma(pAB, wy2[5], acc_b);
        acc_b = __builtin_elementwise_fma(pCD, wy2[6], acc_b);
        acc_b = __builtin_elementwise_fma(pEF, wy2[7], acc_b);
        v2f accs = acc_a + acc_b;
        float R = accs.x + accs.y;

        pb0 = p01.x;         // combined Pb0 for the y0 path (CSE'd readlane)
        z = zbase + R;       // critical-path tail: single add
        V = V + R;           // off-chain, feeds next step's zbase
    };

    // ---- 689 full 64-step blocks ----
    for (int blk = 0; blk < NFULL; ++blk) {
        const int t0 = blk * 64;
        // Next chunk; first touched at the peeled step (63 steps later),
        // so its vmcnt wait is fully hidden.
        float xvn = x[min(t0 + 64 + lane, TM1 - 1) * BATCH + b];
        float outy = 0.f;
        float pb0;

        #pragma unroll 9
        for (int kk = 0; kk < 63; ++kk) {
            STEP(bcast(xv, kk + 1), pb0);
            // y0 path: p0 = pconst0 + Pc0 (full magnitude), b20 at store.
            y0 += pconst0 + pb0;
            outy = (kk == lane) ? y0 : outy;
        }
        // Peeled kk=63: next-x comes from lane 0 of the prefetched chunk.
        STEP(bcast(xvn, 0), pb0);
        y0 += pconst0 + pb0;
        outy = (63 == lane) ? y0 : outy;

        // Store: add back n*b2[0], one IEEE div, coalesced.
        const int n = t0 + 1 + lane;
        out[n * BATCH + b] = fmaf((float)n, b20, outy) / SRATE;
        xv = xvn;
    }

    // ---- tail: 3 steps (n = 44097..44099) ----
    {
        const int t0 = NFULL * 64;              // 44096
        float outy = 0.f;
        float pb0;
        #pragma unroll
        for (int kk = 0; kk < 3; ++kk) {
            STEP(bcast(xv, kk + 1), pb0);
            y0 += pconst0 + pb0;
            outy = (kk == lane) ? y0 : outy;
        }
        if (lane < 3) {
            const int n = t0 + 1 + lane;
            out[n * BATCH + b] = fmaf((float)n, b20, outy) / SRATE;
        }
    }
}

extern "C" void kernel_launch(void* const* d_in, const int* in_sizes, int n_in,
                              void* d_out, int out_size, void* d_ws, size_t ws_size,
                              hipStream_t stream) {
    const float* x  = (const float*)d_in[0];
    const float* W1 = (const float*)d_in[1];
    const float* b1 = (const float*)d_in[2];
    const float* W2 = (const float*)d_in[3];
    const float* b2 = (const float*)d_in[4];
    float* out = (float*)d_out;

    ScaledODENetFE_kernel<<<BATCH, 64, 0, stream>>>(x, W1, b1, W2, b2, out);
}